// Round 6
// baseline (154.445 us; speedup 1.0000x reference)
//
#include <hip/hip_runtime.h>
#include <hip/hip_bf16.h>
#include <stdint.h>

#define TOK   256
#define NOBJ  64
#define NDEMO 16
#define BATCH 256
#define SEQ   1105              /* 1 + 16*65 + 64 */
#define NDG   (NDEMO * BATCH)   /* 4096 demo groups */
#define NGRP  (NDG + BATCH)     /* 4352 total groups */
#define NHT   (NGRP * 2)        /* 8704 half-tiles (32 rows each) */
#define NG    8                 /* half-tiles per obj block */
#define OBJ_BLKS   (NHT / NG)   /* 1088 */
#define ACT_BLKS   512
#define INSTR_BLKS 128
#define TOTAL_BLKS (ACT_BLKS + INSTR_BLKS + OBJ_BLKS)

typedef __bf16 bf16x8 __attribute__((ext_vector_type(8)));
typedef float  f32x4  __attribute__((ext_vector_type(4)));

static __device__ __forceinline__ unsigned pack_bf16x2(float a, float b) {
    unsigned ua = __float_as_uint(a);
    unsigned ub = __float_as_uint(b);
    unsigned ra = (ua + 0x7FFFu + ((ua >> 16) & 1u)) >> 16;
    unsigned rb = (ub + 0x7FFFu + ((ub >> 16) & 1u)) >> 16;
    return (ra & 0xFFFFu) | (rb << 16);
}

static __device__ __forceinline__ uint16_t f32_to_bf16_bits(float a) {
    unsigned ua = __float_as_uint(a);
    return (uint16_t)((ua + 0x7FFFu + ((ua >> 16) & 1u)) >> 16);
}

static __device__ __forceinline__ bf16x8 pack8(float4 lo, float4 hi) {
    union { uint4 u; bf16x8 b; } r;
    r.u.x = pack_bf16x2(lo.x, lo.y);
    r.u.y = pack_bf16x2(lo.z, lo.w);
    r.u.z = pack_bf16x2(hi.x, hi.y);
    r.u.w = pack_bf16x2(hi.z, hi.w);
    return r.b;
}

// direct global->LDS, 16B per lane (dest linear: wave-uniform base + lane*16)
static __device__ __forceinline__ void gload_lds16(const float* g, void* l) {
    __builtin_amdgcn_global_load_lds(
        (const __attribute__((address_space(1))) uint32_t*)g,
        (__attribute__((address_space(3))) uint32_t*)l,
        16, 0, 0);
}

// ---------------------------------------------------------------------------
// Prologue: W_obj (f32 [k=256][t=256]) -> Wf, bf16 in MFMA fragment order:
// chunk q = ((wc*4 + j)*8 + s)*64 + lane  holds Wt[t = wc*64+j*16+(lane&15)]
// [k = s*32+(lane>>4)*8 .. +7], so each wave's B-preload is contiguous 1KB.
// ---------------------------------------------------------------------------
__global__ void wconv_frag_kernel(const float* __restrict__ W, uint16_t* __restrict__ Wf) {
    int q = blockIdx.x * 256 + threadIdx.x;   // 8192 chunks of 16B
    int lane = q & 63;
    int s  = (q >> 6) & 7;
    int j  = (q >> 9) & 3;
    int wc = (q >> 11) & 3;
    int tcol = wc * 64 + j * 16 + (lane & 15);
    int k0   = s * 32 + (lane >> 4) * 8;
    uint4 w;
    unsigned p[4];
#pragma unroll
    for (int h = 0; h < 4; ++h) {
        float a = W[(size_t)(k0 + 2 * h)     * TOK + tcol];
        float b = W[(size_t)(k0 + 2 * h + 1) * TOK + tcol];
        p[h] = pack_bf16x2(a, b);
    }
    w.x = p[0]; w.y = p[1]; w.z = p[2]; w.w = p[3];
    *reinterpret_cast<uint4*>(Wf + (size_t)q * 8) = w;
}

// ---------------------------------------------------------------------------
// Fused kernel. Grid roles:
//   [0, 512)         : action rows (8 per block)
//   [512, 640)       : instr rows (2 per block)
//   [640, 640+1088)  : obj GEMM, NG=8 32-row half-tiles per block,
//                      double-buffered global_load_lds, store-aware vmcnt
// ---------------------------------------------------------------------------
__global__ __launch_bounds__(256, 2) void fused_kernel(
    const float* __restrict__ demo_obj,   // (16,256,64,256)
    const float* __restrict__ cur,        // (256,64,256)
    const float* __restrict__ b_obj,      // (256,)
    const __bf16* __restrict__ Wf,        // fragment-ordered bf16 weights
    const float* __restrict__ demo_act,   // (16,256,7)
    const float* __restrict__ W_act,      // (7,256)
    const float* __restrict__ b_act,      // (256,)
    const float* __restrict__ instr,      // (256,768)
    const float* __restrict__ W_instr,    // (768,256)
    const float* __restrict__ b_instr,    // (256,)
    float* __restrict__ out)              // (256,1105,256)
{
    __shared__ __align__(16) float lds[2 * 32 * TOK];   // 64 KB
    int blk = blockIdx.x;
    int tid = threadIdx.x;

    if (blk >= ACT_BLKS + INSTR_BLKS) {
        // ================= obj GEMM =================
        int ob = blk - (ACT_BLKS + INSTR_BLKS);
        int h0 = ob * NG;
        const float* base = (h0 < 2 * NDG)
            ? demo_obj + (size_t)h0 * (32 * TOK)
            : cur + (size_t)(h0 - 2 * NDG) * (32 * TOK);

        int wave = tid >> 6, lane = tid & 63;
        int l15 = lane & 15, l4 = lane >> 4;
        int n0 = wave * 64;

        int sr = tid >> 6;          // staging row within 4-row stripe
        int sc = tid & 63;          // staging chunk column
        auto STAGE = [&](int it, int bsel) {
            const float* sb = base + (size_t)it * (32 * TOK);
            float* dst = lds + bsel * (32 * TOK);
#pragma unroll
            for (int i = 0; i < 8; ++i) {
                int r = i * 4 + sr;
                int gch = r * 64 + (sc ^ (r & 7));   // pre-swizzled global source
                gload_lds16(sb + (size_t)gch * 4, dst + (size_t)(i * 256 + tid) * 4);
            }
        };

        // ---- B preload FIRST (32 contiguous 1KB wave-loads, 128 VGPR) ----
        bf16x8 bf[4][8];
        {
            const __bf16* fb = Wf + ((size_t)wave * 32 * 64 + lane) * 8;
#pragma unroll
            for (int j = 0; j < 4; ++j)
#pragma unroll
                for (int s = 0; s < 8; ++s)
                    bf[j][s] = *reinterpret_cast<const bf16x8*>(fb + (size_t)(j * 8 + s) * 64 * 8);
        }
        // Launder B through empty asm: compiler's B-wait lands HERE (prologue),
        // so no vmcnt insertion inside the loop for these registers.
#pragma unroll
        for (int j = 0; j < 4; ++j)
#pragma unroll
            for (int s = 0; s < 8; ++s)
                asm volatile("" : "+v"(bf[j][s]));

        // ---- stage first two tiles (16 loads/wave in flight) ----
        STAGE(0, 0);
        STAGE(1, 1);

        float bv[4];
#pragma unroll
        for (int j = 0; j < 4; ++j) bv[j] = b_obj[n0 + j * 16 + l15];

#pragma unroll 1
        for (int it = 0; it < NG; ++it) {
            // Retire own L_it WITHOUT draining previous tile's 32 stores:
            // per-wave outstanding at this point: it==0: L0(8)+L1(8);
            // it>=1: L_it(8, oldest) + S_{it-1}(32, newer).
            if (it == 0) asm volatile("s_waitcnt vmcnt(8)" ::: "memory");
            else         asm volatile("s_waitcnt vmcnt(32)" ::: "memory");
            __builtin_amdgcn_s_barrier();           // raw: no implicit drain
            __builtin_amdgcn_sched_barrier(0);

            // issue next-next stage ASAP (overlaps compute + stores below)
            if (it >= 1 && it + 1 < NG) STAGE(it + 1, (it + 1) & 1);

            const float* buf = lds + (it & 1) * (32 * TOK);

            f32x4 acc[2][4];
#pragma unroll
            for (int i = 0; i < 2; ++i)
#pragma unroll
                for (int j = 0; j < 4; ++j) {
                    f32x4 z = {0.0f, 0.0f, 0.0f, 0.0f};
                    acc[i][j] = z;
                }

#pragma unroll
            for (int s = 0; s < 8; ++s) {
                bf16x8 a[2];
#pragma unroll
                for (int i = 0; i < 2; ++i) {
                    int r = i * 16 + l15;
                    int c0 = s * 8 + l4 * 2;
                    float4 lo = *reinterpret_cast<const float4*>(buf + r * TOK + ((c0 ^ (r & 7)) * 4));
                    float4 hi = *reinterpret_cast<const float4*>(buf + r * TOK + (((c0 + 1) ^ (r & 7)) * 4));
                    a[i] = pack8(lo, hi);
                }
#pragma unroll
                for (int j = 0; j < 4; ++j) {
                    acc[0][j] = __builtin_amdgcn_mfma_f32_16x16x32_bf16(a[0], bf[j][s], acc[0][j], 0, 0, 0);
                    acc[1][j] = __builtin_amdgcn_mfma_f32_16x16x32_bf16(a[1], bf[j][s], acc[1][j], 0, 0, 0);
                }
            }

            // ---- epilogue: bias + store this half-tile (left in flight) ----
            int h = h0 + it;
            int g = h >> 1, half = h & 1;
            int row_base;
            if (h < 2 * NDG) {
                int d = g >> 9, b = (g >> 1 << 1 & 511) >> 1;  // placeholder, fixed below
                (void)d; (void)b;
            }
            {
                int gg = h >> 1;
                if (h < 2 * NDG) {
                    int d = gg >> 8, b = gg & 255;
                    row_base = b * SEQ + 1 + d * (NOBJ + 1) + half * 32;
                } else {
                    int b = gg - NDG;
                    row_base = b * SEQ + 1 + NDEMO * (NOBJ + 1) + half * 32;
                }
            }
#pragma unroll
            for (int i = 0; i < 2; ++i)
#pragma unroll
                for (int j = 0; j < 4; ++j) {
                    int col = n0 + j * 16 + l15;
#pragma unroll
                    for (int r = 0; r < 4; ++r) {
                        int row = row_base + i * 16 + l4 * 4 + r;
                        out[(size_t)row * TOK + col] = acc[i][j][r] + bv[j];
                    }
                }
        }

    } else if (blk < ACT_BLKS) {
        // ================= action rows: 8 consecutive groups =================
        int g8 = blk * 8;
        int t = tid;
        float v[8];
        float bb = b_act[t];
#pragma unroll
        for (int r = 0; r < 8; ++r) v[r] = bb;
#pragma unroll
        for (int k = 0; k < 7; ++k) {
            float wv = W_act[k * TOK + t];
#pragma unroll
            for (int r = 0; r < 8; ++r)
                v[r] += demo_act[(size_t)(g8 + r) * 7 + k] * wv;
        }
#pragma unroll
        for (int r = 0; r < 8; ++r) {
            int g = g8 + r;
            int d = g >> 8, b = g & 255;
            out[(size_t)(b * SEQ + (d + 1) * (NOBJ + 1)) * TOK + t] = v[r];
        }

    } else {
        // ================= instr rows: 2 per block, K=768 =================
        int b0 = (blk - ACT_BLKS) * 2;
        int t = tid;
        float* buf = lds;   // 1536 f32 = 6 KB
        const float* src = instr + (size_t)b0 * 768;
#pragma unroll
        for (int i = 0; i < 6; ++i) buf[i * 256 + t] = src[i * 256 + t];
        __syncthreads();
        float a0 = b_instr[t], a1 = a0;
#pragma unroll 4
        for (int k = 0; k < 768; ++k) {
            float wv = W_instr[(size_t)k * TOK + t];
            a0 += buf[k] * wv;
            a1 += buf[768 + k] * wv;
        }
        out[(size_t)b0 * SEQ * TOK + t] = a0;
        out[(size_t)(b0 + 1) * SEQ * TOK + t] = a1;
    }
}

extern "C" void kernel_launch(void* const* d_in, const int* in_sizes, int n_in,
                              void* d_out, int out_size, void* d_ws, size_t ws_size,
                              hipStream_t stream) {
    (void)in_sizes; (void)n_in; (void)out_size; (void)ws_size;
    const float* instr    = (const float*)d_in[0];
    const float* demo_obj = (const float*)d_in[1];
    const float* demo_act = (const float*)d_in[2];
    const float* cur      = (const float*)d_in[3];
    const float* W_instr  = (const float*)d_in[4];
    const float* b_instr  = (const float*)d_in[5];
    const float* W_act    = (const float*)d_in[6];
    const float* b_act    = (const float*)d_in[7];
    const float* W_obj    = (const float*)d_in[8];
    const float* b_obj    = (const float*)d_in[9];
    float* out = (float*)d_out;

    uint16_t* Wf = (uint16_t*)d_ws;   // 128 KB fragment-ordered bf16 weights

    wconv_frag_kernel<<<32, 256, 0, stream>>>(W_obj, Wf);
    fused_kernel<<<TOTAL_BLKS, 256, 0, stream>>>(
        demo_obj, cur, b_obj, (const __bf16*)d_ws,
        demo_act, W_act, b_act, instr, W_instr, b_instr, out);
}